// Round 1
// 204.977 us; speedup vs baseline: 1.0323x; 1.0323x over previous
//
#include <hip/hip_runtime.h>

#define S_LEN 2048
#define D_DIM 1024
#define NHEAD 16
#define DH 64
#define BATCH 2
#define NROWS (BATCH * S_LEN)  // 4096
#define QSCALE 0.18033688011112042f  // 0.125 * log2(e): scores land in log2 domain

typedef __attribute__((ext_vector_type(8))) short short8;
typedef __attribute__((ext_vector_type(4))) float f32x4;
typedef __attribute__((ext_vector_type(2))) unsigned int u32x2;
typedef __attribute__((ext_vector_type(4))) unsigned int u32x4;

static __device__ __forceinline__ unsigned short f2bf(float f) {
    unsigned int u = __builtin_bit_cast(unsigned int, f);
    u += 0x7fffu + ((u >> 16) & 1u);
    return (unsigned short)(u >> 16);
}
static __device__ __forceinline__ float bf2f(unsigned short h) {
    unsigned int u = ((unsigned int)h) << 16;
    return __builtin_bit_cast(float, u);
}

// ---------------- fp32 -> bf16 convert (inputs + weights) + fused padding masks --------
__global__ __launch_bounds__(256) void cvt_all_kernel(
    const float* __restrict__ s0, const float* __restrict__ s1, const float* __restrict__ s2,
    const float* __restrict__ w0, const float* __restrict__ w1, const float* __restrict__ w2,
    unsigned short* __restrict__ d0, unsigned short* __restrict__ d1,
    unsigned short* __restrict__ d2, unsigned short* __restrict__ e0,
    unsigned short* __restrict__ e1, unsigned short* __restrict__ e2,
    float* __restrict__ qm, float* __restrict__ km) {
    const int y = blockIdx.y;
    const int row = blockIdx.x;
    const int t = threadIdx.x;
    const float* src;
    unsigned short* dst;
    size_t i;
    if (row < NROWS) {
        src = y == 0 ? s0 : (y == 1 ? s1 : s2);
        dst = y == 0 ? d0 : (y == 1 ? d1 : d2);
        i = (size_t)row * 256 + t;
    } else {
        src = y == 0 ? w0 : (y == 1 ? w1 : w2);
        dst = y == 0 ? e0 : (y == 1 ? e1 : e2);
        i = (size_t)(row - NROWS) * 256 + t;
    }
    float4 v = ((const float4*)src)[i];
    ushort4 o;
    o.x = f2bf(v.x); o.y = f2bf(v.y); o.z = f2bf(v.z); o.w = f2bf(v.w);
    ((ushort4*)dst)[i] = o;
    if (row < NROWS && y < 2) {
        float s = v.x + v.y + v.z + v.w;
        for (int off = 1; off < 64; off <<= 1) s += __shfl_xor(s, off);
        __shared__ float red[4];
        const int w = t >> 6;
        if ((t & 63) == 0) red[w] = s;
        __syncthreads();
        if (t == 0) {
            float tt = red[0] + red[1] + red[2] + red[3];
            if (y == 0)
                qm[row] = (tt != 0.0f) ? 1.0f : 0.0f;
            else
                km[row] = (tt != 0.0f) ? 0.0f : -4294967295.0f;
        }
    }
}

// ---------------- fused QKV projection: O = relu(A @ W^T + b), bf16 MFMA ----------------
// Flat 768-block grid, n-major-mod-8 XCD swizzle. z==0 (Q): output scaled by QSCALE.
__global__ __launch_bounds__(256) void proj_kernel(
    const unsigned short* __restrict__ A0, const unsigned short* __restrict__ A1,
    const unsigned short* __restrict__ A2, const unsigned short* __restrict__ W0,
    const unsigned short* __restrict__ W1, const unsigned short* __restrict__ W2,
    const float* __restrict__ b0, const float* __restrict__ b1, const float* __restrict__ b2,
    unsigned short* __restrict__ O0, unsigned short* __restrict__ O1,
    unsigned short* __restrict__ O2) {
    const int u = blockIdx.x;
    const int n = u / 96;
    const int rem = u % 96;
    const int m = rem / 3;
    const int z = rem % 3;
    const unsigned short* A;
    const unsigned short* W;
    const float* bias;
    unsigned short* O;
    if (z == 0) { A = A0; W = W0; bias = b0; O = O0; }
    else if (z == 1) { A = A1; W = W1; bias = b1; O = O1; }
    else { A = A2; W = W2; bias = b2; O = O2; }

    __shared__ __align__(16) unsigned short Asm[128 * 32];
    __shared__ __align__(16) unsigned short Bsm[128 * 32];

    const int t = threadIdx.x;
    const int w = t >> 6, l = t & 63;
    const int quad = l >> 4, lr = l & 15;
    const int wm = w >> 1, wn = w & 1;
    const int m0 = m * 128, n0 = n * 128;

    f32x4 zero = {0.f, 0.f, 0.f, 0.f};
    f32x4 acc[4][4];
#pragma unroll
    for (int i = 0; i < 4; i++)
#pragma unroll
        for (int j = 0; j < 4; j++) acc[i][j] = zero;

    const int c0 = w * 2, c1 = w * 2 + 1;
    const int ar0 = c0 * 16 + (l >> 2), ar1 = c1 * 16 + (l >> 2);
    const int acol = (l & 3) * 8;

    for (int kt = 0; kt < D_DIM / 32; ++kt) {
        const int k0 = kt * 32;
        __syncthreads();
        __builtin_amdgcn_global_load_lds(
            (const __attribute__((address_space(1))) void*)(A + (size_t)(m0 + ar0) * D_DIM + k0 + acol),
            (__attribute__((address_space(3))) void*)(&Asm[c0 * 512]), 16, 0, 0);
        __builtin_amdgcn_global_load_lds(
            (const __attribute__((address_space(1))) void*)(A + (size_t)(m0 + ar1) * D_DIM + k0 + acol),
            (__attribute__((address_space(3))) void*)(&Asm[c1 * 512]), 16, 0, 0);
        __builtin_amdgcn_global_load_lds(
            (const __attribute__((address_space(1))) void*)(W + (size_t)(n0 + ar0) * D_DIM + k0 + acol),
            (__attribute__((address_space(3))) void*)(&Bsm[c0 * 512]), 16, 0, 0);
        __builtin_amdgcn_global_load_lds(
            (const __attribute__((address_space(1))) void*)(W + (size_t)(n0 + ar1) * D_DIM + k0 + acol),
            (__attribute__((address_space(3))) void*)(&Bsm[c1 * 512]), 16, 0, 0);
        __syncthreads();

        short8 af[4], bf[4];
#pragma unroll
        for (int i = 0; i < 4; i++)
            af[i] = *(const short8*)&Asm[(wm * 64 + i * 16 + lr) * 32 + quad * 8];
#pragma unroll
        for (int j = 0; j < 4; j++)
            bf[j] = *(const short8*)&Bsm[(wn * 64 + j * 16 + lr) * 32 + quad * 8];
#pragma unroll
        for (int i = 0; i < 4; i++)
#pragma unroll
            for (int j = 0; j < 4; j++)
                acc[i][j] = __builtin_amdgcn_mfma_f32_16x16x32_bf16(af[i], bf[j], acc[i][j], 0, 0, 0);
    }

    const float oscale = (z == 0) ? QSCALE : 1.0f;
#pragma unroll
    for (int j = 0; j < 4; j++) {
        const int gn = n0 + wn * 64 + j * 16 + lr;
        const float bj = bias[gn];
#pragma unroll
        for (int i = 0; i < 4; i++) {
            const int gmb = m0 + wm * 64 + i * 16 + quad * 4;
#pragma unroll
            for (int r = 0; r < 4; r++) {
                float v = fmaxf(acc[i][j][r] + bj, 0.f) * oscale;
                O[(size_t)(gmb + r) * D_DIM + gn] = f2bf(v);
            }
        }
    }
}

// ---------------- V transpose: (B,S,D) bf16 -> (B,H,dh,S) bf16 (coalesced both ways) ----
__global__ __launch_bounds__(256) void transpose_v(const unsigned short* __restrict__ Vb,
                                                   unsigned short* __restrict__ Vt) {
    __shared__ unsigned short tile[64][65];
    const int s0 = blockIdx.x * 64, h = blockIdx.y, b = blockIdx.z;
    const int t = threadIdx.x;
#pragma unroll
    for (int p = 0; p < 16; p++) {
        int idx = p * 256 + t;
        int si = idx >> 6, ni = idx & 63;
        tile[si][ni] = Vb[(size_t)(b * S_LEN + s0 + si) * D_DIM + h * DH + ni];
    }
    __syncthreads();
#pragma unroll
    for (int p = 0; p < 16; p++) {
        int idx = p * 256 + t;
        int ni = idx >> 6, si = idx & 63;
        Vt[((size_t)(b * NHEAD + h) * DH + ni) * S_LEN + s0 + si] = tile[si][ni];
    }
}

// ---------------- flash attention: swapped-QK^T, zero-LDS P path ------------------------
// grid (63, H, B) = 2016 blocks. 64-row q-tiles, wave = 16 q-rows. LDS 24576 B.
// QK computed as mfma(K,Q): lane (quad,lr) holds P(q=lr, key=16nf+4quad+r) -> P never
// touches LDS. PV uses a custom slot<->key bijection: V b64-reads supply the SAME
// permuted key order, so pa (8 v_perm_b32, trunc-bf16) feeds MFMA A directly.
// km: 1 dword/lane + ballot; penalty-add path is a uniform never-taken branch here.
__global__ __launch_bounds__(256) void attn_kernel(
    const unsigned short* __restrict__ Qb, const unsigned short* __restrict__ Kb,
    const unsigned short* __restrict__ Vt, const float* __restrict__ km_pen,
    unsigned short* __restrict__ oP0, unsigned short* __restrict__ oP1,
    unsigned short* __restrict__ oP2, float* __restrict__ lP) {
    __shared__ __align__(16) unsigned short Ks[2][64 * 64];
    __shared__ __align__(16) unsigned short Vs[64 * 64];

    const int w = threadIdx.x >> 6, l = threadIdx.x & 63;
    const int quad = l >> 4, lr = l & 15;
    const int h = blockIdx.y, b = blockIdx.z;
    const float NEGF = -4294967295.0f;

    // ---- work assignment (LPT: longest first) ----
    int qt, sp;
    const int x = blockIdx.x;
    int ns;
    if (x < 30) { qt = 31 - x / 3; sp = x % 3; ns = 3; }
    else if (x < 52) { int y = x - 30; qt = 21 - y / 2; sp = y % 2; ns = 2; }
    else { qt = 62 - x; sp = 0; ns = 1; }
    const int T = qt + 1;
    const int lo = sp * T / ns, hi = (sp + 1) * T / ns;

    const int q0 = qt * 64;
    const int qbase = q0 + w * 16;

    const int cA = w * 128 + l;
    const int cB = w * 128 + 64 + l;
    const int keyA = cA >> 3, cbA = (cA & 7) ^ (keyA & 7);
    const int keyB = cB >> 3, cbB = (cB & 7) ^ (keyB & 7);
    const unsigned short* Krow = Kb + (size_t)b * S_LEN * D_DIM + h * DH;
    const unsigned short* Vrow = Vt + (size_t)(b * NHEAD + h) * DH * S_LEN;

    // incremental staging pointers (advance per tile)
    const unsigned short* kSA = Krow + (size_t)(lo * 64 + keyA) * D_DIM + cbA * 8;
    const unsigned short* kSB = Krow + (size_t)(lo * 64 + keyB) * D_DIM + cbB * 8;
    const unsigned short* vSA = Vrow + (size_t)keyA * S_LEN + lo * 64 + cbA * 8;
    const unsigned short* vSB = Vrow + (size_t)keyB * S_LEN + lo * 64 + cbB * 8;
    const float* kmrow = km_pen + b * S_LEN + lo * 64 + l;

    unsigned short* const kD0 = &Ks[0][(w * 128) * 8];
    unsigned short* const kD1 = &Ks[0][(w * 128 + 64) * 8];
    unsigned short* const kE0 = &Ks[1][(w * 128) * 8];
    unsigned short* const kE1 = &Ks[1][(w * 128 + 64) * 8];
    unsigned short* const vD0 = &Vs[(w * 128) * 8];
    unsigned short* const vD1 = &Vs[(w * 128 + 64) * 8];

    const unsigned short* qptr = Qb + (size_t)(b * S_LEN + qbase + lr) * D_DIM + h * DH + quad * 8;
    const short8 qf0 = *(const short8*)(qptr);
    const short8 qf1 = *(const short8*)(qptr + 32);

    f32x4 zero = {0.f, 0.f, 0.f, 0.f};
    f32x4 o[4];
#pragma unroll
    for (int j = 0; j < 4; j++) o[j] = zero;
    float l_loc = 0.f;

    const int swz0 = quad ^ (lr & 7);
    const int swz1 = (quad + 4) ^ (lr & 7);

    // precomputed V b64-read byte addresses (slot<->key bijection, swizzle-matched):
    // byte(ks,nf2,j) = (j*16+lr)*128 + ((4ks+2nf2+(quad>>1)) ^ (lr&7))*16 + (quad&1)*8
    int vaddr[2][2];
#pragma unroll
    for (int ks = 0; ks < 2; ks++)
#pragma unroll
        for (int nf2 = 0; nf2 < 2; nf2++)
            vaddr[ks][nf2] = lr * 128 + (quad & 1) * 8 +
                             ((((ks << 2) + (nf2 << 1) + (quad >> 1)) ^ (lr & 7)) << 4);
    const char* const Vsb = (const char*)&Vs[0];
    const int thr = w * 16 + lr - quad * 4;

#define GLDS(src, dst)                                                                  \
    __builtin_amdgcn_global_load_lds((const __attribute__((address_space(1))) void*)(src), \
                                     (__attribute__((address_space(3))) void*)(dst), 16, 0, 0)

    // stage K(lo) into Ks[0]
    GLDS(kSA, kD0);
    GLDS(kSB, kD1);
    kSA += 64 * D_DIM;
    kSB += 64 * D_DIM;

    for (int kt = lo; kt < hi; ++kt) {
        const int cur = (kt - lo) & 1;
        __syncthreads();  // B1: K(kt) staged (drain), prev PV reads of Vs done
        const float kmsel = *kmrow;  // 1 dword, issued BEFORE V GLDS (vmcnt decoupling)
        kmrow += 64;
        GLDS(vSA, vD0);   // V(kt): lands during QK+softmax, drained at B2
        GLDS(vSB, vD1);
        vSA += 64;
        vSB += 64;

        // ---- scores, swapped operands: C[row=key-in-16][col=q=lr] ----
        f32x4 sc[4];
#pragma unroll
        for (int nf = 0; nf < 4; nf++) {
            const int key = nf * 16 + lr;
            const short8 kf0 = *(const short8*)&Ks[cur][(key * 8 + swz0) * 8];
            const short8 kf1 = *(const short8*)&Ks[cur][(key * 8 + swz1) * 8];
            f32x4 z = zero;
            z = __builtin_amdgcn_mfma_f32_16x16x32_bf16(kf0, qf0, z, 0, 0, 0);
            z = __builtin_amdgcn_mfma_f32_16x16x32_bf16(kf1, qf1, z, 0, 0, 0);
            sc[nf] = z;
        }

        const unsigned long long kb = __ballot(kmsel != 0.0f);

        // ---- softmax: bare exp2 (scores bounded); causal only on diagonal tile ----
        float e[4][4];
        if (kt == qt) {
#pragma unroll
            for (int nf = 0; nf < 4; nf++)
#pragma unroll
                for (int r = 0; r < 4; r++)
                    e[nf][r] = (nf * 16 + r <= thr) ? sc[nf][r] : NEGF;
        } else {
#pragma unroll
            for (int nf = 0; nf < 4; nf++)
#pragma unroll
                for (int r = 0; r < 4; r++) e[nf][r] = sc[nf][r];
        }
        if (kb) {  // wave-uniform; cold path (key padding mask present)
#pragma unroll
            for (int nf = 0; nf < 4; nf++) {
                const float4 kmq =
                    *(const float4*)(km_pen + (size_t)b * S_LEN + kt * 64 + nf * 16 + quad * 4);
                e[nf][0] += kmq.x;
                e[nf][1] += kmq.y;
                e[nf][2] += kmq.z;
                e[nf][3] += kmq.w;
            }
        }
#pragma unroll
        for (int nf = 0; nf < 4; nf++) {
#pragma unroll
            for (int r = 0; r < 4; r++) e[nf][r] = exp2f(e[nf][r]);
            l_loc += (e[nf][0] + e[nf][1]) + (e[nf][2] + e[nf][3]);
        }

        // ---- pack P to bf16 A-fragments in-register (trunc via byte-perm) ----
        unsigned int pw[8];
#pragma unroll
        for (int ks = 0; ks < 2; ks++)
#pragma unroll
            for (int p = 0; p < 4; p++) {
                const int nf = 2 * ks + (p >> 1);
                const int r0 = (p & 1) * 2;
                pw[ks * 4 + p] = __builtin_amdgcn_perm(
                    __builtin_bit_cast(unsigned int, e[nf][r0 + 1]),
                    __builtin_bit_cast(unsigned int, e[nf][r0]), 0x07060302u);
            }

        __syncthreads();  // B2: drains V only (K prefetch not yet issued)

        if (kt + 1 < hi) {  // K(kt+1): issued after B2, awaited at next B1
            if (cur) { GLDS(kSA, kD0); GLDS(kSB, kD1); }
            else     { GLDS(kSA, kE0); GLDS(kSB, kE1); }
            kSA += 64 * D_DIM;
            kSB += 64 * D_DIM;
        }

        // ---- PV: V read in the same permuted key order (16x ds_read_b64) ----
#pragma unroll
        for (int ks = 0; ks < 2; ks++) {
            const u32x4 pq = {pw[ks * 4 + 0], pw[ks * 4 + 1], pw[ks * 4 + 2], pw[ks * 4 + 3]};
            const short8 pa = __builtin_bit_cast(short8, pq);
#pragma unroll
            for (int j = 0; j < 4; j++) {
                const u32x2 va = *(const u32x2*)(Vsb + vaddr[ks][0] + j * 2048);
                const u32x2 vb = *(const u32x2*)(Vsb + vaddr[ks][1] + j * 2048);
                const u32x4 vq = {va.x, va.y, vb.x, vb.y};
                const short8 vfj = __builtin_bit_cast(short8, vq);
                o[j] = __builtin_amdgcn_mfma_f32_16x16x32_bf16(pa, vfj, o[j], 0, 0, 0);
            }
        }
    }
#undef GLDS

    // ---- epilogue: bf16 O-partials + fp32 l-partials ----
    float ls = l_loc;
    ls += __shfl_xor(ls, 16);
    ls += __shfl_xor(ls, 32);
    unsigned short* oP = (sp == 0) ? oP0 : ((sp == 1) ? oP1 : oP2);
    if (l < 16)
        lP[sp * (BATCH * NHEAD * S_LEN) + (b * NHEAD + h) * S_LEN + qbase + lr] = ls;
#pragma unroll
    for (int r = 0; r < 4; r++) {
        const int q = qbase + quad * 4 + r;
#pragma unroll
        for (int j = 0; j < 4; j++) {
            oP[(size_t)(b * S_LEN + q) * D_DIM + h * DH + j * 16 + lr] = f2bf(o[j][r]);
        }
    }
}

// ---------------- residual + layernorm + split-K combine (up to 3 partials) ------------
__global__ __launch_bounds__(256) void ln_kernel(
    const unsigned short* __restrict__ oP0, const unsigned short* __restrict__ oP1,
    const unsigned short* __restrict__ oP2, const float* __restrict__ lP,
    const float* __restrict__ qmask, const float* __restrict__ queries,
    const float* __restrict__ gamma, const float* __restrict__ beta,
    float* __restrict__ out) {
    const int row = blockIdx.x;
    const int t = threadIdx.x;
    const int b = row >> 11, q = row & 2047;
    const int qt = q >> 6;  // 64-row q-tiles
    const int ns = (qt <= 10) ? 1 : ((qt <= 21) ? 2 : 3);
    const int h = t >> 4;
    const int lidx = (b * NHEAD + h) * S_LEN + q;
    const int LSTRIDE = BATCH * NHEAD * S_LEN;

    float ls = lP[lidx];
    const size_t ri = (size_t)row * 256 + t;
    const ushort4 a0 = ((const ushort4*)oP0)[ri];
    float sx = bf2f(a0.x), sy = bf2f(a0.y), sz = bf2f(a0.z), sw = bf2f(a0.w);
    if (ns > 1) {
        ls += lP[LSTRIDE + lidx];
        const ushort4 a1 = ((const ushort4*)oP1)[ri];
        sx += bf2f(a1.x); sy += bf2f(a1.y); sz += bf2f(a1.z); sw += bf2f(a1.w);
    }
    if (ns > 2) {
        ls += lP[2 * LSTRIDE + lidx];
        const ushort4 a2 = ((const ushort4*)oP2)[ri];
        sx += bf2f(a2.x); sy += bf2f(a2.y); sz += bf2f(a2.z); sw += bf2f(a2.w);
    }
    const float qmr = qmask[row];
    const float inv0 = (ls > 0.f) ? qmr / ls : 0.f;

    const float4 qv = ((const float4*)(queries + (size_t)row * D_DIM))[t];
    float4 x;
    x.x = sx * inv0 + qv.x;
    x.y = sy * inv0 + qv.y;
    x.z = sz * inv0 + qv.z;
    x.w = sw * inv0 + qv.w;

    float s = x.x + x.y + x.z + x.w;
    float sq = x.x * x.x + x.y * x.y + x.z * x.z + x.w * x.w;
    for (int o = 1; o < 64; o <<= 1) { s += __shfl_xor(s, o); sq += __shfl_xor(sq, o); }
    __shared__ float rs[4], rq[4];
    const int w = t >> 6;
    if ((t & 63) == 0) { rs[w] = s; rq[w] = sq; }
    __syncthreads();
    s = rs[0] + rs[1] + rs[2] + rs[3];
    sq = rq[0] + rq[1] + rq[2] + rq[3];
    const float mean = s * (1.0f / 1024.0f);
    float var = (sq - s * mean) * (1.0f / 1023.0f);
    var = fmaxf(var, 0.f);
    const float inv = 1.0f / (sqrtf(var) + 1e-8f);
    const float4 g = ((const float4*)gamma)[t];
    const float4 bb = ((const float4*)beta)[t];
    float4 y;
    y.x = g.x * (x.x - mean) * inv + bb.x;
    y.y = g.y * (x.y - mean) * inv + bb.y;
    y.z = g.z * (x.z - mean) * inv + bb.z;
    y.w = g.w * (x.w - mean) * inv + bb.w;
    ((float4*)(out + (size_t)row * D_DIM))[t] = y;
}

extern "C" void kernel_launch(void* const* d_in, const int* in_sizes, int n_in, void* d_out,
                              int out_size, void* d_ws, size_t ws_size, hipStream_t stream) {
    const float* queries = (const float*)d_in[0];
    const float* keys = (const float*)d_in[1];
    const float* values = (const float*)d_in[2];
    const float* Wq = (const float*)d_in[3];
    const float* bq = (const float*)d_in[4];
    const float* Wk = (const float*)d_in[5];
    const float* bk = (const float*)d_in[6];
    const float* Wv = (const float*)d_in[7];
    const float* bv = (const float*)d_in[8];
    const float* gamma = (const float*)d_in[9];
    const float* beta = (const float*)d_in[10];
    float* out = (float*)d_out;
    char* ws = (char*)d_ws;

    const size_t MB = 1048576;
    unsigned short* qin = (unsigned short*)(ws + 0);
    unsigned short* kin = (unsigned short*)(ws + 8 * MB);
    unsigned short* vin = (unsigned short*)(ws + 16 * MB);
    unsigned short* wqb = (unsigned short*)(ws + 24 * MB);
    unsigned short* wkb = (unsigned short*)(ws + 26 * MB);
    unsigned short* wvb = (unsigned short*)(ws + 28 * MB);
    unsigned short* Qb = (unsigned short*)(ws + 30 * MB);
    unsigned short* Kb = (unsigned short*)(ws + 38 * MB);
    unsigned short* Vb = (unsigned short*)(ws + 46 * MB);
    unsigned short* Vt = (unsigned short*)(ws + 0);          // aliases qin (dead after proj)
    unsigned short* oP0 = (unsigned short*)(ws + 16 * MB);   // aliases vin (dead)
    unsigned short* oP1 = (unsigned short*)(ws + 46 * MB);   // aliases Vb (dead after transpose)
    unsigned short* oP2 = (unsigned short*)(ws + 8 * MB);    // aliases kin (dead)
    float* qm = (float*)(ws + 54 * MB);
    float* km = (float*)(ws + 54 * MB + 16384);
    float* lP = (float*)(ws + 54 * MB + 32768);  // 3 x 65536 fp32 = 768KB

    cvt_all_kernel<<<dim3(NROWS + D_DIM, 3), 256, 0, stream>>>(
        queries, keys, values, Wq, Wk, Wv, qin, kin, vin, wqb, wkb, wvb, qm, km);

    proj_kernel<<<768, 256, 0, stream>>>(
        qin, kin, vin, wqb, wkb, wvb, bq, bk, bv, Qb, Kb, Vb);

    transpose_v<<<dim3(S_LEN / 64, NHEAD, BATCH), 256, 0, stream>>>(Vb, Vt);

    attn_kernel<<<dim3(63, NHEAD, BATCH), 256, 0, stream>>>(Qb, Kb, Vt, km, oP0, oP1, oP2, lP);

    ln_kernel<<<NROWS, 256, 0, stream>>>(oP0, oP1, oP2, lP, qm, queries, gamma, beta, out);
}

// Round 2
// 198.494 us; speedup vs baseline: 1.0661x; 1.0327x over previous
//
#include <hip/hip_runtime.h>

#define S_LEN 2048
#define D_DIM 1024
#define NHEAD 16
#define DH 64
#define BATCH 2
#define NROWS (BATCH * S_LEN)  // 4096
#define QSCALE 0.18033688011112042f  // 0.125 * log2(e): scores land in log2 domain

typedef __attribute__((ext_vector_type(8))) short short8;
typedef __attribute__((ext_vector_type(4))) float f32x4;
typedef __attribute__((ext_vector_type(2))) unsigned int u32x2;
typedef __attribute__((ext_vector_type(4))) unsigned int u32x4;

static __device__ __forceinline__ unsigned short f2bf(float f) {
    unsigned int u = __builtin_bit_cast(unsigned int, f);
    u += 0x7fffu + ((u >> 16) & 1u);
    return (unsigned short)(u >> 16);
}
static __device__ __forceinline__ float bf2f(unsigned short h) {
    unsigned int u = ((unsigned int)h) << 16;
    return __builtin_bit_cast(float, u);
}

// ---------------- fp32 -> bf16 convert (inputs + weights) + fused padding masks --------
__global__ __launch_bounds__(256) void cvt_all_kernel(
    const float* __restrict__ s0, const float* __restrict__ s1, const float* __restrict__ s2,
    const float* __restrict__ w0, const float* __restrict__ w1, const float* __restrict__ w2,
    unsigned short* __restrict__ d0, unsigned short* __restrict__ d1,
    unsigned short* __restrict__ d2, unsigned short* __restrict__ e0,
    unsigned short* __restrict__ e1, unsigned short* __restrict__ e2,
    float* __restrict__ qm, float* __restrict__ km) {
    const int y = blockIdx.y;
    const int row = blockIdx.x;
    const int t = threadIdx.x;
    const float* src;
    unsigned short* dst;
    size_t i;
    if (row < NROWS) {
        src = y == 0 ? s0 : (y == 1 ? s1 : s2);
        dst = y == 0 ? d0 : (y == 1 ? d1 : d2);
        i = (size_t)row * 256 + t;
    } else {
        src = y == 0 ? w0 : (y == 1 ? w1 : w2);
        dst = y == 0 ? e0 : (y == 1 ? e1 : e2);
        i = (size_t)(row - NROWS) * 256 + t;
    }
    float4 v = ((const float4*)src)[i];
    ushort4 o;
    o.x = f2bf(v.x); o.y = f2bf(v.y); o.z = f2bf(v.z); o.w = f2bf(v.w);
    ((ushort4*)dst)[i] = o;
    if (row < NROWS && y < 2) {
        float s = v.x + v.y + v.z + v.w;
        for (int off = 1; off < 64; off <<= 1) s += __shfl_xor(s, off);
        __shared__ float red[4];
        const int w = t >> 6;
        if ((t & 63) == 0) red[w] = s;
        __syncthreads();
        if (t == 0) {
            float tt = red[0] + red[1] + red[2] + red[3];
            if (y == 0)
                qm[row] = (tt != 0.0f) ? 1.0f : 0.0f;
            else
                km[row] = (tt != 0.0f) ? 0.0f : -4294967295.0f;
        }
    }
}

// ---------------- fused QKV projection: O = relu(A @ W^T + b), bf16 MFMA ----------------
// Flat 768-block grid, n-major-mod-8 XCD swizzle. z==0 (Q): output scaled by QSCALE.
__global__ __launch_bounds__(256) void proj_kernel(
    const unsigned short* __restrict__ A0, const unsigned short* __restrict__ A1,
    const unsigned short* __restrict__ A2, const unsigned short* __restrict__ W0,
    const unsigned short* __restrict__ W1, const unsigned short* __restrict__ W2,
    const float* __restrict__ b0, const float* __restrict__ b1, const float* __restrict__ b2,
    unsigned short* __restrict__ O0, unsigned short* __restrict__ O1,
    unsigned short* __restrict__ O2) {
    const int u = blockIdx.x;
    const int n = u / 96;
    const int rem = u % 96;
    const int m = rem / 3;
    const int z = rem % 3;
    const unsigned short* A;
    const unsigned short* W;
    const float* bias;
    unsigned short* O;
    if (z == 0) { A = A0; W = W0; bias = b0; O = O0; }
    else if (z == 1) { A = A1; W = W1; bias = b1; O = O1; }
    else { A = A2; W = W2; bias = b2; O = O2; }

    __shared__ __align__(16) unsigned short Asm[128 * 32];
    __shared__ __align__(16) unsigned short Bsm[128 * 32];

    const int t = threadIdx.x;
    const int w = t >> 6, l = t & 63;
    const int quad = l >> 4, lr = l & 15;
    const int wm = w >> 1, wn = w & 1;
    const int m0 = m * 128, n0 = n * 128;

    f32x4 zero = {0.f, 0.f, 0.f, 0.f};
    f32x4 acc[4][4];
#pragma unroll
    for (int i = 0; i < 4; i++)
#pragma unroll
        for (int j = 0; j < 4; j++) acc[i][j] = zero;

    const int c0 = w * 2, c1 = w * 2 + 1;
    const int ar0 = c0 * 16 + (l >> 2), ar1 = c1 * 16 + (l >> 2);
    const int acol = (l & 3) * 8;

    for (int kt = 0; kt < D_DIM / 32; ++kt) {
        const int k0 = kt * 32;
        __syncthreads();
        __builtin_amdgcn_global_load_lds(
            (const __attribute__((address_space(1))) void*)(A + (size_t)(m0 + ar0) * D_DIM + k0 + acol),
            (__attribute__((address_space(3))) void*)(&Asm[c0 * 512]), 16, 0, 0);
        __builtin_amdgcn_global_load_lds(
            (const __attribute__((address_space(1))) void*)(A + (size_t)(m0 + ar1) * D_DIM + k0 + acol),
            (__attribute__((address_space(3))) void*)(&Asm[c1 * 512]), 16, 0, 0);
        __builtin_amdgcn_global_load_lds(
            (const __attribute__((address_space(1))) void*)(W + (size_t)(n0 + ar0) * D_DIM + k0 + acol),
            (__attribute__((address_space(3))) void*)(&Bsm[c0 * 512]), 16, 0, 0);
        __builtin_amdgcn_global_load_lds(
            (const __attribute__((address_space(1))) void*)(W + (size_t)(n0 + ar1) * D_DIM + k0 + acol),
            (__attribute__((address_space(3))) void*)(&Bsm[c1 * 512]), 16, 0, 0);
        __syncthreads();

        short8 af[4], bf[4];
#pragma unroll
        for (int i = 0; i < 4; i++)
            af[i] = *(const short8*)&Asm[(wm * 64 + i * 16 + lr) * 32 + quad * 8];
#pragma unroll
        for (int j = 0; j < 4; j++)
            bf[j] = *(const short8*)&Bsm[(wn * 64 + j * 16 + lr) * 32 + quad * 8];
#pragma unroll
        for (int i = 0; i < 4; i++)
#pragma unroll
            for (int j = 0; j < 4; j++)
                acc[i][j] = __builtin_amdgcn_mfma_f32_16x16x32_bf16(af[i], bf[j], acc[i][j], 0, 0, 0);
    }

    const float oscale = (z == 0) ? QSCALE : 1.0f;
#pragma unroll
    for (int j = 0; j < 4; j++) {
        const int gn = n0 + wn * 64 + j * 16 + lr;
        const float bj = bias[gn];
#pragma unroll
        for (int i = 0; i < 4; i++) {
            const int gmb = m0 + wm * 64 + i * 16 + quad * 4;
#pragma unroll
            for (int r = 0; r < 4; r++) {
                float v = fmaxf(acc[i][j][r] + bj, 0.f) * oscale;
                O[(size_t)(gmb + r) * D_DIM + gn] = f2bf(v);
            }
        }
    }
}

// ---------------- V transpose: (B,S,D) bf16 -> (B,H,dh,S) bf16 (coalesced both ways) ----
__global__ __launch_bounds__(256) void transpose_v(const unsigned short* __restrict__ Vb,
                                                   unsigned short* __restrict__ Vt) {
    __shared__ unsigned short tile[64][65];
    const int s0 = blockIdx.x * 64, h = blockIdx.y, b = blockIdx.z;
    const int t = threadIdx.x;
#pragma unroll
    for (int p = 0; p < 16; p++) {
        int idx = p * 256 + t;
        int si = idx >> 6, ni = idx & 63;
        tile[si][ni] = Vb[(size_t)(b * S_LEN + s0 + si) * D_DIM + h * DH + ni];
    }
    __syncthreads();
#pragma unroll
    for (int p = 0; p < 16; p++) {
        int idx = p * 256 + t;
        int ni = idx >> 6, si = idx & 63;
        Vt[((size_t)(b * NHEAD + h) * DH + ni) * S_LEN + s0 + si] = tile[si][ni];
    }
}

// ---------------- flash attention: swapped-QK^T, zero-LDS P path ------------------------
// grid (63, H, B) = 2016 blocks. 64-row q-tiles, wave = 16 q-rows. LDS 24576 B.
// QK computed as mfma(K,Q): lane (quad,lr) holds P(q=lr, key=16nf+4quad+r).
// PV: permlane16_swap exchanges half-runs so quad q owns contiguous keys
// {8*bitrev2(q)..+7} -> V read as conflict-free ds_read_b128 (K-path pattern, 0 conflicts)
// instead of R1's 16x b64 gather (4 extra conflict cycles/read, 4.3M total).
// exp2: raw v_exp_f32 (scores in log2 domain; flush-to-zero is wanted) - no OCML fixup.
__global__ __launch_bounds__(256) void attn_kernel(
    const unsigned short* __restrict__ Qb, const unsigned short* __restrict__ Kb,
    const unsigned short* __restrict__ Vt, const float* __restrict__ km_pen,
    unsigned short* __restrict__ oP0, unsigned short* __restrict__ oP1,
    unsigned short* __restrict__ oP2, float* __restrict__ lP) {
    __shared__ __align__(16) unsigned short Ks[2][64 * 64];
    __shared__ __align__(16) unsigned short Vs[64 * 64];

    const int w = threadIdx.x >> 6, l = threadIdx.x & 63;
    const int quad = l >> 4, lr = l & 15;
    const int h = blockIdx.y, b = blockIdx.z;
    const float NEGF = -4294967295.0f;

    // ---- work assignment (LPT: longest first) ----
    int qt, sp;
    const int x = blockIdx.x;
    int ns;
    if (x < 30) { qt = 31 - x / 3; sp = x % 3; ns = 3; }
    else if (x < 52) { int y = x - 30; qt = 21 - y / 2; sp = y % 2; ns = 2; }
    else { qt = 62 - x; sp = 0; ns = 1; }
    const int T = qt + 1;
    const int lo = sp * T / ns, hi = (sp + 1) * T / ns;

    const int q0 = qt * 64;
    const int qbase = q0 + w * 16;

    const int cA = w * 128 + l;
    const int cB = w * 128 + 64 + l;
    const int keyA = cA >> 3, cbA = (cA & 7) ^ (keyA & 7);
    const int keyB = cB >> 3, cbB = (cB & 7) ^ (keyB & 7);
    const unsigned short* Krow = Kb + (size_t)b * S_LEN * D_DIM + h * DH;
    const unsigned short* Vrow = Vt + (size_t)(b * NHEAD + h) * DH * S_LEN;

    // incremental staging pointers (advance per tile)
    const unsigned short* kSA = Krow + (size_t)(lo * 64 + keyA) * D_DIM + cbA * 8;
    const unsigned short* kSB = Krow + (size_t)(lo * 64 + keyB) * D_DIM + cbB * 8;
    const unsigned short* vSA = Vrow + (size_t)keyA * S_LEN + lo * 64 + cbA * 8;
    const unsigned short* vSB = Vrow + (size_t)keyB * S_LEN + lo * 64 + cbB * 8;
    const float* kmrow = km_pen + b * S_LEN + lo * 64 + l;

    unsigned short* const kD0 = &Ks[0][(w * 128) * 8];
    unsigned short* const kD1 = &Ks[0][(w * 128 + 64) * 8];
    unsigned short* const kE0 = &Ks[1][(w * 128) * 8];
    unsigned short* const kE1 = &Ks[1][(w * 128 + 64) * 8];
    unsigned short* const vD0 = &Vs[(w * 128) * 8];
    unsigned short* const vD1 = &Vs[(w * 128 + 64) * 8];

    const unsigned short* qptr = Qb + (size_t)(b * S_LEN + qbase + lr) * D_DIM + h * DH + quad * 8;
    const short8 qf0 = *(const short8*)(qptr);
    const short8 qf1 = *(const short8*)(qptr + 32);

    f32x4 zero = {0.f, 0.f, 0.f, 0.f};
    f32x4 o[4];
#pragma unroll
    for (int j = 0; j < 4; j++) o[j] = zero;
    float l_loc = 0.f;

    const int swz0 = quad ^ (lr & 7);
    const int swz1 = (quad + 4) ^ (lr & 7);

    // V b128 read base: lane (quad,lr) reads group (d=16j+lr, sc=4ks+m(quad)),
    // m(quad)=bitrev2(quad); byte = lr*128 + ((m^(lr&7))<<4), ks toggles bit 6.
    const int mq = ((quad & 1) << 1) | (quad >> 1);
    const int voff0 = lr * 128 + ((mq ^ (lr & 7)) << 4);
    const char* const Vsb = (const char*)&Vs[0];
    const int thr = w * 16 + lr - quad * 4;

#define GLDS(src, dst)                                                                  \
    __builtin_amdgcn_global_load_lds((const __attribute__((address_space(1))) void*)(src), \
                                     (__attribute__((address_space(3))) void*)(dst), 16, 0, 0)

    // stage K(lo) into Ks[0]
    GLDS(kSA, kD0);
    GLDS(kSB, kD1);
    kSA += 64 * D_DIM;
    kSB += 64 * D_DIM;

    for (int kt = lo; kt < hi; ++kt) {
        const int cur = (kt - lo) & 1;
        __syncthreads();  // B1: K(kt) staged (drain), prev PV reads of Vs done
        const float kmsel = *kmrow;  // 1 dword, issued BEFORE V GLDS (vmcnt decoupling)
        kmrow += 64;
        GLDS(vSA, vD0);   // V(kt): lands during QK+softmax, drained at B2
        GLDS(vSB, vD1);
        vSA += 64;
        vSB += 64;

        // ---- scores, swapped operands: C[row=key-in-16][col=q=lr] ----
        f32x4 sc[4];
#pragma unroll
        for (int nf = 0; nf < 4; nf++) {
            const int key = nf * 16 + lr;
            const short8 kf0 = *(const short8*)&Ks[cur][(key * 8 + swz0) * 8];
            const short8 kf1 = *(const short8*)&Ks[cur][(key * 8 + swz1) * 8];
            f32x4 z = zero;
            z = __builtin_amdgcn_mfma_f32_16x16x32_bf16(kf0, qf0, z, 0, 0, 0);
            z = __builtin_amdgcn_mfma_f32_16x16x32_bf16(kf1, qf1, z, 0, 0, 0);
            sc[nf] = z;
        }

        const unsigned long long kb = __ballot(kmsel != 0.0f);

        // ---- softmax: bare exp2 (scores bounded); causal only on diagonal tile ----
        float e[4][4];
        if (kt == qt) {
#pragma unroll
            for (int nf = 0; nf < 4; nf++)
#pragma unroll
                for (int r = 0; r < 4; r++)
                    e[nf][r] = (nf * 16 + r <= thr) ? sc[nf][r] : NEGF;
        } else {
#pragma unroll
            for (int nf = 0; nf < 4; nf++)
#pragma unroll
                for (int r = 0; r < 4; r++) e[nf][r] = sc[nf][r];
        }
        if (kb) {  // wave-uniform; cold path (key padding mask present)
#pragma unroll
            for (int nf = 0; nf < 4; nf++) {
                const float4 kmq =
                    *(const float4*)(km_pen + (size_t)b * S_LEN + kt * 64 + nf * 16 + quad * 4);
                e[nf][0] += kmq.x;
                e[nf][1] += kmq.y;
                e[nf][2] += kmq.z;
                e[nf][3] += kmq.w;
            }
        }
#pragma unroll
        for (int nf = 0; nf < 4; nf++) {
#pragma unroll
            for (int r = 0; r < 4; r++) e[nf][r] = __builtin_amdgcn_exp2f(e[nf][r]);
            l_loc += (e[nf][0] + e[nf][1]) + (e[nf][2] + e[nf][3]);
        }

        // ---- pack P to bf16 in-register (trunc via byte-perm) ----
        unsigned int pw[8];
#pragma unroll
        for (int ks = 0; ks < 2; ks++)
#pragma unroll
            for (int p = 0; p < 4; p++) {
                const int nf = 2 * ks + (p >> 1);
                const int r0 = (p & 1) * 2;
                pw[ks * 4 + p] = __builtin_amdgcn_perm(
                    __builtin_bit_cast(unsigned int, e[nf][r0 + 1]),
                    __builtin_bit_cast(unsigned int, e[nf][r0]), 0x07060302u);
            }

        __syncthreads();  // B2: drains V only (K prefetch not yet issued)

        if (kt + 1 < hi) {  // K(kt+1): issued after B2, awaited at next B1
            if (cur) { GLDS(kSA, kD0); GLDS(kSB, kD1); }
            else     { GLDS(kSA, kE0); GLDS(kSB, kE1); }
            kSA += 64 * D_DIM;
            kSB += 64 * D_DIM;
        }

        // ---- PV: permlane16_swap -> contiguous 8-key runs -> conflict-free b128 V ----
#pragma unroll
        for (int ks = 0; ks < 2; ks++) {
            const u32x2 s0 = __builtin_amdgcn_permlane16_swap(pw[ks * 4 + 0], pw[ks * 4 + 2],
                                                              false, false);
            const u32x2 s1 = __builtin_amdgcn_permlane16_swap(pw[ks * 4 + 1], pw[ks * 4 + 3],
                                                              false, false);
            const u32x4 pq = {s0[0], s1[0], s0[1], s1[1]};
            const short8 pa = __builtin_bit_cast(short8, pq);
            const int off = voff0 ^ (ks << 6);
#pragma unroll
            for (int j = 0; j < 4; j++) {
                const short8 vfj = *(const short8*)(Vsb + off + j * 2048);
                o[j] = __builtin_amdgcn_mfma_f32_16x16x32_bf16(pa, vfj, o[j], 0, 0, 0);
            }
        }
    }
#undef GLDS

    // ---- epilogue: bf16 O-partials + fp32 l-partials ----
    float ls = l_loc;
    ls += __shfl_xor(ls, 16);
    ls += __shfl_xor(ls, 32);
    unsigned short* oP = (sp == 0) ? oP0 : ((sp == 1) ? oP1 : oP2);
    if (l < 16)
        lP[sp * (BATCH * NHEAD * S_LEN) + (b * NHEAD + h) * S_LEN + qbase + lr] = ls;
#pragma unroll
    for (int r = 0; r < 4; r++) {
        const int q = qbase + quad * 4 + r;
#pragma unroll
        for (int j = 0; j < 4; j++) {
            oP[(size_t)(b * S_LEN + q) * D_DIM + h * DH + j * 16 + lr] = f2bf(o[j][r]);
        }
    }
}

// ---------------- residual + layernorm + split-K combine (up to 3 partials) ------------
__global__ __launch_bounds__(256) void ln_kernel(
    const unsigned short* __restrict__ oP0, const unsigned short* __restrict__ oP1,
    const unsigned short* __restrict__ oP2, const float* __restrict__ lP,
    const float* __restrict__ qmask, const float* __restrict__ queries,
    const float* __restrict__ gamma, const float* __restrict__ beta,
    float* __restrict__ out) {
    const int row = blockIdx.x;
    const int t = threadIdx.x;
    const int b = row >> 11, q = row & 2047;
    const int qt = q >> 6;  // 64-row q-tiles
    const int ns = (qt <= 10) ? 1 : ((qt <= 21) ? 2 : 3);
    const int h = t >> 4;
    const int lidx = (b * NHEAD + h) * S_LEN + q;
    const int LSTRIDE = BATCH * NHEAD * S_LEN;

    float ls = lP[lidx];
    const size_t ri = (size_t)row * 256 + t;
    const ushort4 a0 = ((const ushort4*)oP0)[ri];
    float sx = bf2f(a0.x), sy = bf2f(a0.y), sz = bf2f(a0.z), sw = bf2f(a0.w);
    if (ns > 1) {
        ls += lP[LSTRIDE + lidx];
        const ushort4 a1 = ((const ushort4*)oP1)[ri];
        sx += bf2f(a1.x); sy += bf2f(a1.y); sz += bf2f(a1.z); sw += bf2f(a1.w);
    }
    if (ns > 2) {
        ls += lP[2 * LSTRIDE + lidx];
        const ushort4 a2 = ((const ushort4*)oP2)[ri];
        sx += bf2f(a2.x); sy += bf2f(a2.y); sz += bf2f(a2.z); sw += bf2f(a2.w);
    }
    const float qmr = qmask[row];
    const float inv0 = (ls > 0.f) ? qmr / ls : 0.f;

    const float4 qv = ((const float4*)(queries + (size_t)row * D_DIM))[t];
    float4 x;
    x.x = sx * inv0 + qv.x;
    x.y = sy * inv0 + qv.y;
    x.z = sz * inv0 + qv.z;
    x.w = sw * inv0 + qv.w;

    float s = x.x + x.y + x.z + x.w;
    float sq = x.x * x.x + x.y * x.y + x.z * x.z + x.w * x.w;
    for (int o = 1; o < 64; o <<= 1) { s += __shfl_xor(s, o); sq += __shfl_xor(sq, o); }
    __shared__ float rs[4], rq[4];
    const int w = t >> 6;
    if ((t & 63) == 0) { rs[w] = s; rq[w] = sq; }
    __syncthreads();
    s = rs[0] + rs[1] + rs[2] + rs[3];
    sq = rq[0] + rq[1] + rq[2] + rq[3];
    const float mean = s * (1.0f / 1024.0f);
    float var = (sq - s * mean) * (1.0f / 1023.0f);
    var = fmaxf(var, 0.f);
    const float inv = 1.0f / (sqrtf(var) + 1e-8f);
    const float4 g = ((const float4*)gamma)[t];
    const float4 bb = ((const float4*)beta)[t];
    float4 y;
    y.x = g.x * (x.x - mean) * inv + bb.x;
    y.y = g.y * (x.y - mean) * inv + bb.y;
    y.z = g.z * (x.z - mean) * inv + bb.z;
    y.w = g.w * (x.w - mean) * inv + bb.w;
    ((float4*)(out + (size_t)row * D_DIM))[t] = y;
}

extern "C" void kernel_launch(void* const* d_in, const int* in_sizes, int n_in, void* d_out,
                              int out_size, void* d_ws, size_t ws_size, hipStream_t stream) {
    const float* queries = (const float*)d_in[0];
    const float* keys = (const float*)d_in[1];
    const float* values = (const float*)d_in[2];
    const float* Wq = (const float*)d_in[3];
    const float* bq = (const float*)d_in[4];
    const float* Wk = (const float*)d_in[5];
    const float* bk = (const float*)d_in[6];
    const float* Wv = (const float*)d_in[7];
    const float* bv = (const float*)d_in[8];
    const float* gamma = (const float*)d_in[9];
    const float* beta = (const float*)d_in[10];
    float* out = (float*)d_out;
    char* ws = (char*)d_ws;

    const size_t MB = 1048576;
    unsigned short* qin = (unsigned short*)(ws + 0);
    unsigned short* kin = (unsigned short*)(ws + 8 * MB);
    unsigned short* vin = (unsigned short*)(ws + 16 * MB);
    unsigned short* wqb = (unsigned short*)(ws + 24 * MB);
    unsigned short* wkb = (unsigned short*)(ws + 26 * MB);
    unsigned short* wvb = (unsigned short*)(ws + 28 * MB);
    unsigned short* Qb = (unsigned short*)(ws + 30 * MB);
    unsigned short* Kb = (unsigned short*)(ws + 38 * MB);
    unsigned short* Vb = (unsigned short*)(ws + 46 * MB);
    unsigned short* Vt = (unsigned short*)(ws + 0);          // aliases qin (dead after proj)
    unsigned short* oP0 = (unsigned short*)(ws + 16 * MB);   // aliases vin (dead)
    unsigned short* oP1 = (unsigned short*)(ws + 46 * MB);   // aliases Vb (dead after transpose)
    unsigned short* oP2 = (unsigned short*)(ws + 8 * MB);    // aliases kin (dead)
    float* qm = (float*)(ws + 54 * MB);
    float* km = (float*)(ws + 54 * MB + 16384);
    float* lP = (float*)(ws + 54 * MB + 32768);  // 3 x 65536 fp32 = 768KB

    cvt_all_kernel<<<dim3(NROWS + D_DIM, 3), 256, 0, stream>>>(
        queries, keys, values, Wq, Wk, Wv, qin, kin, vin, wqb, wkb, wvb, qm, km);

    proj_kernel<<<768, 256, 0, stream>>>(
        qin, kin, vin, wqb, wkb, wvb, bq, bk, bv, Qb, Kb, Vb);

    transpose_v<<<dim3(S_LEN / 64, NHEAD, BATCH), 256, 0, stream>>>(Vb, Vt);

    attn_kernel<<<dim3(63, NHEAD, BATCH), 256, 0, stream>>>(Qb, Kb, Vt, km, oP0, oP1, oP2, lP);

    ln_kernel<<<NROWS, 256, 0, stream>>>(oP0, oP1, oP2, lP, qm, queries, gamma, beta, out);
}